// Round 16
// baseline (280.038 us; speedup 1.0000x reference)
//
#include <hip/hip_runtime.h>
#include <math.h>

#define N_NODES 50000
#define SN      N_NODES               // sentinel node id for CSR pads
#define E_RAW   1600000
#define TE      (E_RAW + N_NODES)     // 1650000 edges incl. self loops
#define TEP     (TE + 16 * N_NODES)   // CSR padded to 16-aligned rows (upper bound)
#define F_IN    128
#define H1      4
#define F1      128                   // H1*C1
#define F2      64
#define NEG_SLOPE 0.2f
#define EPS_F   1e-16f
#define XPAD    136                   // LDS row stride in bf16 (kills bank conflicts)

// ---- bucket-sort CSR build params (all atomics are LDS-scope) ----
#define NBINS   196                   // coarse buckets: dst >> 8
#define NBLK_A  128                   // blocks in coarse hist/scatter
#define EPB     ((TE + NBLK_A - 1) / NBLK_A)
#define MM_BLOCKS (N_NODES / 16)      // 3125

__device__ __forceinline__ float lrelu(float v) { return v > 0.f ? v : NEG_SLOPE * v; }

typedef float vf2 __attribute__((ext_vector_type(2)));
typedef short short8 __attribute__((ext_vector_type(8)));
typedef float f32x4 __attribute__((ext_vector_type(4)));

__device__ __forceinline__ unsigned short f2bf(float f) {
    unsigned u = __float_as_uint(f);
    return (unsigned short)((u + 0x7fffu + ((u >> 16) & 1u)) >> 16);
}
__device__ __forceinline__ unsigned bfpack(float lo, float hi) {   // 2 bf16 in a uint
    return ((unsigned)f2bf(lo)) | (((unsigned)f2bf(hi)) << 16);
}
__device__ __forceinline__ unsigned char f2fp8(float f) {
    int p = __builtin_amdgcn_cvt_pk_fp8_f32(f, f, 0, false);
    return (unsigned char)(p & 0xff);
}
__device__ __forceinline__ vf2 fp8lo(unsigned u) {   // bytes 0,1 -> 2 floats
    return __builtin_amdgcn_cvt_pk_f32_fp8((int)u, false);
}
__device__ __forceinline__ vf2 fp8hi(unsigned u) {   // bytes 2,3 -> 2 floats
    return __builtin_amdgcn_cvt_pk_f32_fp8((int)u, true);
}

// ---------------- prep: W -> transposed bf16 [c][k]; sentinel logits ---------
__global__ __launch_bounds__(256) void k_prep(const float* __restrict__ W1,
                                              const float* __restrict__ W2,
                                              unsigned short* __restrict__ w1t,
                                              unsigned short* __restrict__ w2t,
                                              float* __restrict__ a1s,
                                              float* __restrict__ a2s) {
    int idx = blockIdx.x * 256 + threadIdx.x;   // 96 blocks: 16384 + 8192
    if (idx < 16384) {
        int c = idx >> 7, k = idx & 127;
        w1t[idx] = f2bf(W1[k * F1 + c]);
    } else {
        int j = idx - 16384;
        int c = j >> 7, k = j & 127;
        w2t[j] = f2bf(W2[k * F2 + c]);
    }
    if (blockIdx.x == 0 && threadIdx.x < H1) a1s[SN * H1 + threadIdx.x] = -1e30f;
    if (blockIdx.x == 0 && threadIdx.x == H1) a2s[SN] = -1e30f;
}

// ---------------- layer1 matmul via MFMA (+ fused coarse histogram) ----------
__global__ __launch_bounds__(256) void k_l1_mm_hist(
    const float* __restrict__ x, const unsigned short* __restrict__ w1t,
    const float* __restrict__ atts, const float* __restrict__ attd,
    unsigned char* __restrict__ xwf8, float* __restrict__ a1s, float* __restrict__ a1d,
    const int* __restrict__ ei, int* __restrict__ cnt) {
    __shared__ __align__(16) unsigned short wls[F1 * XPAD];
    __shared__ __align__(16) unsigned short xs[16 * XPAD];
    const int t = threadIdx.x;
    if (blockIdx.x >= MM_BLOCKS) {
        int* hist = (int*)wls;
        const int blk = blockIdx.x - MM_BLOCKS;
        for (int i = t; i < NBINS; i += 256) hist[i] = 0;
        __syncthreads();
        const int e0 = blk * EPB, e1 = min(TE, e0 + EPB);
        for (int e = e0 + t; e < e1; e += 256) {
            int d = (e < E_RAW) ? ei[E_RAW + e] : (e - E_RAW);
            atomicAdd(&hist[d >> 8], 1);
        }
        __syncthreads();
        for (int i = t; i < NBINS; i += 256) cnt[i * NBLK_A + blk] = hist[i];
        return;
    }
    const int n0 = blockIdx.x * 16;
    {
        const float4* src = (const float4*)(x + (size_t)n0 * F_IN);
#pragma unroll
        for (int i = 0; i < 2; ++i) {
            int idx = t + 256 * i;
            float4 v = src[idx];
            int row = idx >> 5;
            int col = (idx & 31) * 4;
            ushort4 o = { f2bf(v.x), f2bf(v.y), f2bf(v.z), f2bf(v.w) };
            *(ushort4*)(xs + row * XPAD + col) = o;
        }
        const uint4* wsrc = (const uint4*)w1t;
#pragma unroll
        for (int i = 0; i < 8; ++i) {
            int idx = t + 256 * i;
            uint4 v = wsrc[idx];
            int row = idx >> 4;
            int col = (idx & 15) * 8;
            *(uint4*)(wls + row * XPAD + col) = v;
        }
    }
    __syncthreads();
    const int w = t >> 6;         // wave = head
    const int lane = t & 63;
    const int quad = lane >> 4;
    const int ncol = lane & 15;
    const int ch0 = w * 32;
    const unsigned short* arow = xs + ncol * XPAD;
    const unsigned short* brow0 = wls + (ch0 + ncol) * XPAD;
    const unsigned short* brow1 = brow0 + 16 * XPAD;
    f32x4 acc0 = {0.f, 0.f, 0.f, 0.f}, acc1 = {0.f, 0.f, 0.f, 0.f};
#pragma unroll
    for (int s = 0; s < 4; ++s) {
        int kb = s * 32 + quad * 8;
        short8 a  = *(const short8*)(arow + kb);
        short8 b0 = *(const short8*)(brow0 + kb);
        short8 b1 = *(const short8*)(brow1 + kb);
        acc0 = __builtin_amdgcn_mfma_f32_16x16x32_bf16(a, b0, acc0, 0, 0, 0);
        acc1 = __builtin_amdgcn_mfma_f32_16x16x32_bf16(a, b1, acc1, 0, 0, 0);
    }
    const int ch = ch0 + ncol;
    const float as0 = atts[ch], as1 = atts[ch + 16];
    const float ad0 = attd[ch], ad1 = attd[ch + 16];
#pragma unroll
    for (int reg = 0; reg < 4; ++reg) {
        const int n = n0 + quad * 4 + reg;
        float v0 = acc0[reg], v1 = acc1[reg];
        xwf8[(size_t)n * F1 + ch] = f2fp8(v0);
        xwf8[(size_t)n * F1 + ch + 16] = f2fp8(v1);
        float ps = fmaf(v0, as0, v1 * as1);
        float pd = fmaf(v0, ad0, v1 * ad1);
#pragma unroll
        for (int off = 1; off < 16; off <<= 1) {
            ps += __shfl_xor(ps, off);
            pd += __shfl_xor(pd, off);
        }
        if (ncol == 0) {
            a1s[n * H1 + w] = ps;
            a1d[n * H1 + w] = pd;
        }
    }
}

// ---------------- per-bin scan of cnt across blocks + bin totals -------------
__global__ __launch_bounds__(64) void k_btot(int* __restrict__ cnt, int* __restrict__ btot) {
    const int bin = blockIdx.x, lane = threadIdx.x;
    int c0 = cnt[bin * NBLK_A + 2 * lane];
    int c1 = cnt[bin * NBLK_A + 2 * lane + 1];
    int s = c0 + c1;
    int incl = s;
#pragma unroll
    for (int off = 1; off < 64; off <<= 1) {
        int u = __shfl_up(incl, off, 64);
        if (lane >= off) incl += u;
    }
    int excl = incl - s;
    cnt[bin * NBLK_A + 2 * lane] = excl;
    cnt[bin * NBLK_A + 2 * lane + 1] = excl + c0;
    if (lane == 63) btot[bin] = incl;
}

// ---------------- exclusive scan of 196 bin totals -> bucket_start -----------
__global__ __launch_bounds__(64) void k_bstart(const int* __restrict__ btot,
                                               int* __restrict__ bstart) {
    const int lane = threadIdx.x;
    int v[4]; int s = 0;
#pragma unroll
    for (int j = 0; j < 4; ++j) {
        int i = 4 * lane + j;
        v[j] = (i < NBINS) ? btot[i] : 0;
        s += v[j];
    }
    int incl = s;
#pragma unroll
    for (int off = 1; off < 64; off <<= 1) {
        int u = __shfl_up(incl, off, 64);
        if (lane >= off) incl += u;
    }
    int run = incl - s;
#pragma unroll
    for (int j = 0; j < 4; ++j) {
        int i = 4 * lane + j;
        if (i < NBINS) bstart[i] = run;
        run += v[j];
    }
    if (lane == 63) bstart[NBINS] = TE;
}

// ---------------- scatter into coarse buckets (plain stores) -----------------
__global__ __launch_bounds__(256) void k_scatter_coarse(const int* __restrict__ ei,
                                                        const int* __restrict__ cnt,
                                                        const int* __restrict__ bstart,
                                                        unsigned* __restrict__ cbuf) {
    __shared__ int cur[NBINS];
    const int t = threadIdx.x, blk = blockIdx.x;
    for (int i = t; i < NBINS; i += 256) cur[i] = cnt[i * NBLK_A + blk] + bstart[i];
    __syncthreads();
    const int e0 = blk * EPB, e1 = min(TE, e0 + EPB);
    for (int e = e0 + t; e < e1; e += 256) {
        int s, d;
        if (e < E_RAW) { s = ei[e]; d = ei[E_RAW + e]; }
        else { s = e - E_RAW; d = s; }
        int pos = atomicAdd(&cur[d >> 8], 1);   // LDS atomic
        cbuf[pos] = ((unsigned)(d & 255) << 16) | (unsigned)s;
    }
}

// ---------------- fine histogram -> deg --------------------
__global__ __launch_bounds__(256) void k_fine_hist(const unsigned* __restrict__ cbuf,
                                                   const int* __restrict__ bstart,
                                                   int* __restrict__ deg) {
    __shared__ int hist[256];
    const int t = threadIdx.x, b = blockIdx.x;
    hist[t] = 0;
    __syncthreads();
    const int i0 = bstart[b], i1 = bstart[b + 1];
    for (int i = i0 + t; i < i1; i += 256) atomicAdd(&hist[cbuf[i] >> 16], 1);
    __syncthreads();
    const int d = b * 256 + t;
    if (d < N_NODES) deg[d] = hist[t];
}

// ---------------- exclusive scan over 16-PADDED degrees (2-level) ------------
__global__ __launch_bounds__(1024) void k_scan1(const int* __restrict__ deg,
                                                int* __restrict__ incl, int* __restrict__ bsum) {
    int t = threadIdx.x, g = blockIdx.x;
    int idx = g * 1024 + t;
    int v = (idx < N_NODES) ? ((deg[idx] + 15) & ~15) : 0;
    int lane = t & 63, w = t >> 6;
#pragma unroll
    for (int off = 1; off < 64; off <<= 1) {
        int u = __shfl_up(v, off, 64);
        if (lane >= off) v += u;
    }
    __shared__ int ws[16];
    if (lane == 63) ws[w] = v;
    __syncthreads();
    if (w == 0 && lane < 16) {
        int s = ws[lane];
#pragma unroll
        for (int off = 1; off < 16; off <<= 1) {
            int u = __shfl_up(s, off, 16);
            if (lane >= off) s += u;
        }
        ws[lane] = s;
    }
    __syncthreads();
    if (w > 0) v += ws[w - 1];
    if (idx < N_NODES) incl[idx] = v;
    if (t == 1023) bsum[g] = v;
}

__global__ void k_scan2(int* __restrict__ bsum, int nblk) {
    int t = threadIdx.x;
    int v = (t < nblk) ? bsum[t] : 0;
#pragma unroll
    for (int off = 1; off < 64; off <<= 1) {
        int u = __shfl_up(v, off, 64);
        if (t >= off) v += u;
    }
    if (t < nblk) bsum[t] = v;
}

__global__ __launch_bounds__(1024) void k_scan3(const int* __restrict__ incl,
                                                const int* __restrict__ bsum,
                                                int* __restrict__ rowstart) {
    int idx = blockIdx.x * 1024 + threadIdx.x;
    if (idx >= N_NODES) return;
    int off = (blockIdx.x > 0) ? bsum[blockIdx.x - 1] : 0;
    rowstart[idx + 1] = incl[idx] + off;
    if (idx == 0) rowstart[0] = 0;
}

// ---------------- per-bucket scatter into csr + sentinel pad fill ------------
__global__ __launch_bounds__(256) void k_build_csr(const unsigned* __restrict__ cbuf,
                                                   const int* __restrict__ bstart,
                                                   const int* __restrict__ rowstart,
                                                   const int* __restrict__ deg,
                                                   int* __restrict__ csr) {
    __shared__ int cur[256];
    const int t = threadIdx.x, b = blockIdx.x;
    const int d = b * 256 + t;
    cur[t] = (d < N_NODES) ? rowstart[d] : 0;
    __syncthreads();
    const int i0 = bstart[b], i1 = bstart[b + 1];
    for (int i = i0 + t; i < i1; i += 256) {
        unsigned v = cbuf[i];
        int pos = atomicAdd(&cur[v >> 16], 1);   // LDS atomic
        csr[pos] = (int)(v & 0xffffu);
    }
    __syncthreads();
    if (d < N_NODES) {
        const int pend = rowstart[d] + ((deg[d] + 15) & ~15);
        for (int i = cur[t]; i < pend; ++i) csr[i] = SN;
    }
}

// ---------------- layer1 gather: 8ch/lane uint2 gathers, pk-FMA --------------
// Quarter q owns edges 4q..4q+3 of each 16-edge block; lane (q,sub) covers
// channels 8sub..8sub+7 (one uint2 = 8 fp8 per gather -> 4 gathers/iter).
// Weight producer: lane p=(h*16+e) computes exp for edge e=lane&15, head
// h=lane>>4; consumer (q,sub) fetches w[4q+j][sub>>2] via __shfl.
// Accumulate in vf2 pairs -> v_pk_fma_f32. h1 stored bf16 (same RNE values
// k_l2_mm previously converted to -> zero accuracy change, half the traffic).
__global__ __launch_bounds__(256) void k_l1_gather(
    const int* __restrict__ rowstart, const int* __restrict__ csr,
    const int* __restrict__ deg, const float* __restrict__ a1s,
    const float* __restrict__ a1d, const uint2* __restrict__ xwv,
    const float* __restrict__ b1, unsigned* __restrict__ h1bf) {
    const int lane = threadIdx.x & 63;
    const int wid = threadIdx.x >> 6;
    const int n = blockIdx.x * 4 + wid;
    if (n >= N_NODES) return;
    const int rs = rowstart[n];
    const int nb16 = (deg[n] + 15) >> 4;
    const int q = lane >> 4;
    const int sub = lane & 15;              // channels 8sub..8sub+7
    const float adh = a1d[n * H1 + q];      // producer head = q
    const int wbase = (sub >> 2) * 16 + 4 * q;  // consumer's shuffle source base
    const int4* c4 = (const int4*)(csr + rs);
    vf2 f01 = {0.f, 0.f}, f23 = {0.f, 0.f}, f45 = {0.f, 0.f}, f67 = {0.f, 0.f};
    float den = 0.f;
    for (int b = 0; b < nb16; ++b) {
        int4 sQ = c4[4 * b + q];                 // edges 4q..4q+3
        int se = csr[rs + 16 * b + sub];         // producer's weight edge
        uint2 u0 = xwv[sQ.x * 16 + sub], u1 = xwv[sQ.y * 16 + sub];
        uint2 u2 = xwv[sQ.z * 16 + sub], u3 = xwv[sQ.w * 16 + sub];
        float we = __expf(lrelu(a1s[se * H1 + q] + adh));
        float w0 = __shfl(we, wbase + 0), w1 = __shfl(we, wbase + 1);
        float w2 = __shfl(we, wbase + 2), w3 = __shfl(we, wbase + 3);
        den += (w0 + w1) + (w2 + w3);
        vf2 wv;
        wv[0] = w0; wv[1] = w0;
        f01 = __builtin_elementwise_fma(wv, fp8lo(u0.x), f01);
        f23 = __builtin_elementwise_fma(wv, fp8hi(u0.x), f23);
        f45 = __builtin_elementwise_fma(wv, fp8lo(u0.y), f45);
        f67 = __builtin_elementwise_fma(wv, fp8hi(u0.y), f67);
        wv[0] = w1; wv[1] = w1;
        f01 = __builtin_elementwise_fma(wv, fp8lo(u1.x), f01);
        f23 = __builtin_elementwise_fma(wv, fp8hi(u1.x), f23);
        f45 = __builtin_elementwise_fma(wv, fp8lo(u1.y), f45);
        f67 = __builtin_elementwise_fma(wv, fp8hi(u1.y), f67);
        wv[0] = w2; wv[1] = w2;
        f01 = __builtin_elementwise_fma(wv, fp8lo(u2.x), f01);
        f23 = __builtin_elementwise_fma(wv, fp8hi(u2.x), f23);
        f45 = __builtin_elementwise_fma(wv, fp8lo(u2.y), f45);
        f67 = __builtin_elementwise_fma(wv, fp8hi(u2.y), f67);
        wv[0] = w3; wv[1] = w3;
        f01 = __builtin_elementwise_fma(wv, fp8lo(u3.x), f01);
        f23 = __builtin_elementwise_fma(wv, fp8hi(u3.x), f23);
        f45 = __builtin_elementwise_fma(wv, fp8lo(u3.y), f45);
        f67 = __builtin_elementwise_fma(wv, fp8hi(u3.y), f67);
    }
#pragma unroll
    for (int off = 16; off <= 32; off <<= 1) {
        f01[0] += __shfl_xor(f01[0], off); f01[1] += __shfl_xor(f01[1], off);
        f23[0] += __shfl_xor(f23[0], off); f23[1] += __shfl_xor(f23[1], off);
        f45[0] += __shfl_xor(f45[0], off); f45[1] += __shfl_xor(f45[1], off);
        f67[0] += __shfl_xor(f67[0], off); f67[1] += __shfl_xor(f67[1], off);
        den += __shfl_xor(den, off);
    }
    if (q == 0) {
        const float inv = 1.f / (den + EPS_F);
        float4 b0 = ((const float4*)b1)[2 * sub];
        float4 b1v = ((const float4*)b1)[2 * sub + 1];
        float o0 = fmaf(f01[0], inv, b0.x), o1 = fmaf(f01[1], inv, b0.y);
        float o2 = fmaf(f23[0], inv, b0.z), o3 = fmaf(f23[1], inv, b0.w);
        float o4 = fmaf(f45[0], inv, b1v.x), o5 = fmaf(f45[1], inv, b1v.y);
        float o6 = fmaf(f67[0], inv, b1v.z), o7 = fmaf(f67[1], inv, b1v.w);
        o0 = o0 > 0.f ? o0 : expm1f(o0);
        o1 = o1 > 0.f ? o1 : expm1f(o1);
        o2 = o2 > 0.f ? o2 : expm1f(o2);
        o3 = o3 > 0.f ? o3 : expm1f(o3);
        o4 = o4 > 0.f ? o4 : expm1f(o4);
        o5 = o5 > 0.f ? o5 : expm1f(o5);
        o6 = o6 > 0.f ? o6 : expm1f(o6);
        o7 = o7 > 0.f ? o7 : expm1f(o7);
        uint4 pk = { bfpack(o0, o1), bfpack(o2, o3), bfpack(o4, o5), bfpack(o6, o7) };
        ((uint4*)h1bf)[(size_t)n * 16 + sub] = pk;
    }
}

// ---------------- layer2 matmul via MFMA (bf16 h1 in, fp8 out) ---------------
__global__ __launch_bounds__(256) void k_l2_mm(
    const unsigned* __restrict__ h1bf, const unsigned short* __restrict__ w2t,
    const float* __restrict__ atts, const float* __restrict__ attd,
    unsigned char* __restrict__ xwf8, float* __restrict__ a2s, float* __restrict__ a2d) {
    __shared__ __align__(16) unsigned short wls[F2 * XPAD];
    __shared__ __align__(16) unsigned short xs[16 * XPAD];
    __shared__ float parts[16][4], partd[16][4];
    const int t = threadIdx.x;
    const int n0 = blockIdx.x * 16;
    {
        const uint4* src = (const uint4*)(h1bf + (size_t)n0 * 64);  // 256 uint4
        uint4 v = src[t];
        int row = t >> 4;
        int col = (t & 15) * 8;
        *(uint4*)(xs + row * XPAD + col) = v;
        const uint4* wsrc = (const uint4*)w2t;
#pragma unroll
        for (int i = 0; i < 4; ++i) {
            int idx = t + 256 * i;
            uint4 wv = wsrc[idx];
            int wrow = idx >> 4;
            int wcol = (idx & 15) * 8;
            *(uint4*)(wls + wrow * XPAD + wcol) = wv;
        }
    }
    __syncthreads();
    const int w = t >> 6;
    const int lane = t & 63;
    const int quad = lane >> 4;
    const int ncol = lane & 15;
    const int ch0 = w * 16;
    const unsigned short* arow = xs + ncol * XPAD;
    const unsigned short* brow = wls + (ch0 + ncol) * XPAD;
    f32x4 acc = {0.f, 0.f, 0.f, 0.f};
#pragma unroll
    for (int s = 0; s < 4; ++s) {
        int kb = s * 32 + quad * 8;
        short8 a = *(const short8*)(arow + kb);
        short8 b = *(const short8*)(brow + kb);
        acc = __builtin_amdgcn_mfma_f32_16x16x32_bf16(a, b, acc, 0, 0, 0);
    }
    const int ch = ch0 + ncol;
    const float asv = atts[ch], adv = attd[ch];
#pragma unroll
    for (int reg = 0; reg < 4; ++reg) {
        const int m = quad * 4 + reg;
        float v = acc[reg];
        xwf8[(size_t)(n0 + m) * F2 + ch] = f2fp8(v);
        float ps = v * asv, pd = v * adv;
#pragma unroll
        for (int off = 1; off < 16; off <<= 1) {
            ps += __shfl_xor(ps, off);
            pd += __shfl_xor(pd, off);
        }
        if (ncol == 0) { parts[m][w] = ps; partd[m][w] = pd; }
    }
    __syncthreads();
    if (t < 16) {
        a2s[n0 + t] = (parts[t][0] + parts[t][1]) + (parts[t][2] + parts[t][3]);
        a2d[n0 + t] = (partd[t][0] + partd[t][1]) + (partd[t][2] + partd[t][3]);
    }
}

// ---------------- layer2 gather: 8ch/lane uint2 gathers, pk-FMA --------------
// Octant g owns edges 2g,2g+1 of each 16-edge block; lane (g,sub) covers
// channels 8sub..8sub+7. Weight producer: lane computes exp for edge lane&15.
__global__ __launch_bounds__(256) void k_l2_gather(
    const int* __restrict__ rowstart, const int* __restrict__ csr,
    const int* __restrict__ deg, const float* __restrict__ a2s,
    const float* __restrict__ a2d, const uint2* __restrict__ xwv,
    float* __restrict__ h2) {
    const int lane = threadIdx.x & 63;
    const int wid = threadIdx.x >> 6;
    const int n = blockIdx.x * 4 + wid;
    if (n >= N_NODES) return;
    const int rs = rowstart[n];
    const int nb16 = (deg[n] + 15) >> 4;
    const int g = lane >> 3;
    const int sub = lane & 7;               // channels 8sub..8sub+7
    const float adv = a2d[n];
    const int2* c2 = (const int2*)(csr + rs);
    vf2 f01 = {0.f, 0.f}, f23 = {0.f, 0.f}, f45 = {0.f, 0.f}, f67 = {0.f, 0.f};
    float den = 0.f;
    for (int b = 0; b < nb16; ++b) {
        int2 sG = c2[8 * b + g];                 // edges 2g, 2g+1
        int se = csr[rs + 16 * b + (lane & 15)]; // producer's weight edge
        uint2 u0 = xwv[sG.x * 8 + sub], u1 = xwv[sG.y * 8 + sub];
        float we = __expf(lrelu(a2s[se] + adv));
        float w0 = __shfl(we, 2 * g), w1 = __shfl(we, 2 * g + 1);
        den += w0 + w1;
        vf2 wv;
        wv[0] = w0; wv[1] = w0;
        f01 = __builtin_elementwise_fma(wv, fp8lo(u0.x), f01);
        f23 = __builtin_elementwise_fma(wv, fp8hi(u0.x), f23);
        f45 = __builtin_elementwise_fma(wv, fp8lo(u0.y), f45);
        f67 = __builtin_elementwise_fma(wv, fp8hi(u0.y), f67);
        wv[0] = w1; wv[1] = w1;
        f01 = __builtin_elementwise_fma(wv, fp8lo(u1.x), f01);
        f23 = __builtin_elementwise_fma(wv, fp8hi(u1.x), f23);
        f45 = __builtin_elementwise_fma(wv, fp8lo(u1.y), f45);
        f67 = __builtin_elementwise_fma(wv, fp8hi(u1.y), f67);
    }
#pragma unroll
    for (int off = 8; off <= 32; off <<= 1) {
        f01[0] += __shfl_xor(f01[0], off); f01[1] += __shfl_xor(f01[1], off);
        f23[0] += __shfl_xor(f23[0], off); f23[1] += __shfl_xor(f23[1], off);
        f45[0] += __shfl_xor(f45[0], off); f45[1] += __shfl_xor(f45[1], off);
        f67[0] += __shfl_xor(f67[0], off); f67[1] += __shfl_xor(f67[1], off);
        den += __shfl_xor(den, off);
    }
    if (lane < 8) {
        const float inv = 1.f / (den + EPS_F);
        float4 o0 = make_float4(f01[0] * inv, f01[1] * inv, f23[0] * inv, f23[1] * inv);
        float4 o1 = make_float4(f45[0] * inv, f45[1] * inv, f67[0] * inv, f67[1] * inv);
        ((float4*)h2)[(size_t)n * 16 + 2 * sub] = o0;
        ((float4*)h2)[(size_t)n * 16 + 2 * sub + 1] = o1;
    }
}

// ---------------- mean over nodes (fp64 accum) ----------------
#define MEAN_BLOCKS 256
__global__ __launch_bounds__(256) void k_mean(const float* __restrict__ h2,
                                              double* __restrict__ accum) {
    const int t = threadIdx.x;
    const int c = t & 63;
    double acc = 0.0;
    const size_t total = (size_t)N_NODES * F2;
    for (size_t idx = (size_t)blockIdx.x * 256 + t; idx < total; idx += (size_t)MEAN_BLOCKS * 256)
        acc += (double)h2[idx];
    __shared__ double red[256];
    red[t] = acc;
    __syncthreads();
    if (t < 64) {
        double v = red[t] + red[t + 64] + red[t + 128] + red[t + 192];
        atomicAdd(&accum[c], v);
    }
}

__global__ void k_final(const double* __restrict__ accum, const float* __restrict__ b2,
                        float* __restrict__ out) {
    int t = threadIdx.x;
    if (t < F2) out[t] = (float)(accum[t] * (1.0 / (double)N_NODES)) + b2[t];
}

// ---------------- launch ----------------
extern "C" void kernel_launch(void* const* d_in, const int* in_sizes, int n_in,
                              void* d_out, int out_size, void* d_ws, size_t ws_size,
                              hipStream_t stream) {
    (void)in_sizes; (void)n_in; (void)out_size; (void)ws_size;
    const float* x   = (const float*)d_in[0];
    const int*   ei  = (const int*)d_in[1];
    const float* W1  = (const float*)d_in[2];
    const float* as1 = (const float*)d_in[3];
    const float* ad1 = (const float*)d_in[4];
    const float* b1  = (const float*)d_in[5];
    const float* W2  = (const float*)d_in[6];
    const float* as2 = (const float*)d_in[7];
    const float* ad2 = (const float*)d_in[8];
    const float* b2  = (const float*)d_in[9];
    float* out = (float*)d_out;

    char* ws = (char*)d_ws;
    size_t off = 0;
    auto alloc = [&](size_t bytes) -> void* {
        void* p = ws + off;
        off += (bytes + 255) & ~(size_t)255;
        return p;
    };
    unsigned char*  xw1f8 = (unsigned char*)alloc((size_t)(N_NODES + 1) * F1);
    unsigned* h1bf  = (unsigned*)alloc((size_t)N_NODES * F1 * 2);
    unsigned char*  xw2f8 = (unsigned char*)alloc((size_t)(N_NODES + 1) * F2);
    float* h2       = (float*)alloc((size_t)N_NODES * F2 * 4);
    unsigned short* w1t = (unsigned short*)alloc((size_t)F1 * F1 * 2);
    unsigned short* w2t = (unsigned short*)alloc((size_t)F2 * F1 * 2);
    float* a1s      = (float*)alloc((size_t)(N_NODES + 1) * H1 * 4);
    float* a1d      = (float*)alloc((size_t)N_NODES * H1 * 4);
    float* a2s      = (float*)alloc((size_t)(N_NODES + 1) * 4);
    float* a2d      = (float*)alloc((size_t)N_NODES * 4);
    int*   deg      = (int*)alloc((size_t)N_NODES * 4);
    unsigned* cbuf  = (unsigned*)alloc((size_t)TE * 4);
    int*   cnt      = (int*)alloc((size_t)NBINS * NBLK_A * 4);
    int*   btot     = (int*)alloc((size_t)NBINS * 4);
    int*   bstart   = (int*)alloc((size_t)(NBINS + 1) * 4);
    int*   rowstart = (int*)alloc((size_t)(N_NODES + 1) * 4);
    int*   csr      = (int*)alloc((size_t)TEP * 4);
    int*   incl     = (int*)alloc((size_t)N_NODES * 4);
    int*   bsum     = (int*)alloc(64 * 4);
    double* accum   = (double*)alloc(F2 * 8);

    const int nscan = (N_NODES + 1023) / 1024;  // 49
    const int nwave4 = (N_NODES + 3) / 4;       // 12500

    hipMemsetAsync(accum, 0, F2 * 8, stream);
    k_prep<<<96, 256, 0, stream>>>(W1, W2, w1t, w2t, a1s, a2s);
    k_l1_mm_hist<<<MM_BLOCKS + NBLK_A, 256, 0, stream>>>(x, w1t, as1, ad1, xw1f8, a1s, a1d, ei, cnt);
    k_btot<<<NBINS, 64, 0, stream>>>(cnt, btot);
    k_bstart<<<1, 64, 0, stream>>>(btot, bstart);
    k_scatter_coarse<<<NBLK_A, 256, 0, stream>>>(ei, cnt, bstart, cbuf);
    k_fine_hist<<<NBINS, 256, 0, stream>>>(cbuf, bstart, deg);
    k_scan1<<<nscan, 1024, 0, stream>>>(deg, incl, bsum);
    k_scan2<<<1, 64, 0, stream>>>(bsum, nscan);
    k_scan3<<<nscan, 1024, 0, stream>>>(incl, bsum, rowstart);
    k_build_csr<<<NBINS, 256, 0, stream>>>(cbuf, bstart, rowstart, deg, csr);
    k_l1_gather<<<nwave4, 256, 0, stream>>>(rowstart, csr, deg, a1s, a1d,
                                            (const uint2*)xw1f8, b1, h1bf);
    k_l2_mm<<<MM_BLOCKS, 256, 0, stream>>>(h1bf, w2t, as2, ad2, xw2f8, a2s, a2d);
    k_l2_gather<<<nwave4, 256, 0, stream>>>(rowstart, csr, deg, a2s, a2d,
                                            (const uint2*)xw2f8, h2);
    k_mean<<<MEAN_BLOCKS, 256, 0, stream>>>(h2, accum);
    k_final<<<1, 64, 0, stream>>>(accum, b2, out);
}